// Round 12
// baseline (248.135 us; speedup 1.0000x reference)
//
#include <hip/hip_runtime.h>
#include <hip/hip_bf16.h>

// FusedColorMLP: out = relu(relu(enc @ W1) @ W2) @ W3
// enc = [SH-deg4(x[:, :3]) (16) | x[:, 3:19] (16)]  -> 32 features
// bf16 MFMA (16x16x32), fp32 accumulate. 2 independent 16-pt tiles/iter.
// R11: wave-private fencing + load pipelining.
//  - LDS buffers are wave-private -> s_barrier unnecessary. Replace
//    __syncthreads() with {asm lgkmcnt(0); sched_barrier(0)} per guide
//    rule #18 (R6's divergence == the documented MFMA-hoist hazard;
//    sched_barrier(0) is the documented fix).
//  - lgkm-only fences don't drain vmcnt -> iter i+1's 16 x-loads issue
//    at the top of iter i and fly across the whole iteration (~1500 cyc
//    cover vs ~100 before). #pragma unroll 2 keeps the double-buffer
//    statically indexed (rule #20).
// R10 post-mortem: 2-tile ILP matched prediction (113.9 -> ~86us).
// R9 lesson: never force occupancy below weight-resident VGPR count.

typedef short short8 __attribute__((ext_vector_type(8)));
typedef short short4v __attribute__((ext_vector_type(4)));
typedef float f32x4 __attribute__((ext_vector_type(4)));

#define MFMA16(a, b, c) __builtin_amdgcn_mfma_f32_16x16x32_bf16((a), (b), (c), 0, 0, 0)

// Intra-wave LDS write->read fence: drain lgkm, then pin the schedule so
// no register-only op (MFMA) is hoisted above the drain (guide rule #18).
#define WAVE_LDS_FENCE()                                   \
  do {                                                     \
    asm volatile("s_waitcnt lgkmcnt(0)" ::: "memory");     \
    __builtin_amdgcn_sched_barrier(0);                     \
  } while (0)

static __device__ __forceinline__ short f2bf(float f) {
  __hip_bfloat16 h = __float2bfloat16(f);  // RNE
  return __builtin_bit_cast(short, h);
}

#define LDS_PAD 68   // row stride in bf16 elems: 136B (2-way alias: free)
#define ITERS 8      // 2 tiles x 16 pts x 8 iters = 256 pts per wave

__global__ __launch_bounds__(256, 4) void fused_color_mlp(
    const float* __restrict__ x, const float* __restrict__ W1,
    const float* __restrict__ W2, const float* __restrict__ W3,
    float* __restrict__ out, int N) {
  __shared__ short h1s[4][2][16][LDS_PAD];
  __shared__ short h2s[4][2][16][LDS_PAD];

  const int tid = threadIdx.x;
  const int wv = tid >> 6;      // wave in block
  const int lane = tid & 63;
  const int row = lane & 15;    // A row / B,C col
  const int kg = lane >> 4;     // k-group (8 consecutive k per lane)

  // ---- one-time: weight B-fragments in registers (56 VGPRs) ----
  // B layout: lane holds col = lane&15, k = 32*s + 8*kg + j
  short8 w1b[4];
#pragma unroll
  for (int cb = 0; cb < 4; ++cb) {
    short8 t;
#pragma unroll
    for (int j = 0; j < 8; ++j) t[j] = f2bf(W1[(kg * 8 + j) * 64 + cb * 16 + row]);
    w1b[cb] = t;
  }
  short8 w2b[2][4];
#pragma unroll
  for (int s = 0; s < 2; ++s)
#pragma unroll
    for (int cb = 0; cb < 4; ++cb) {
      short8 t;
#pragma unroll
      for (int j = 0; j < 8; ++j)
        t[j] = f2bf(W2[(s * 32 + kg * 8 + j) * 64 + cb * 16 + row]);
      w2b[s][cb] = t;
    }
  // W3 (64x3) zero-padded to 16 cols; clamped index: speculation-safe.
  short8 w3b[2];
  const int c3r = (row < 3) ? row : 2;
#pragma unroll
  for (int s = 0; s < 2; ++s) {
    short8 t;
#pragma unroll
    for (int j = 0; j < 8; ++j) {
      short w = f2bf(W3[(s * 32 + kg * 8 + j) * 3 + c3r]);
      t[j] = (row < 3) ? w : (short)0;
    }
    w3b[s] = t;
  }

  const f32x4 zero = {0.f, 0.f, 0.f, 0.f};
  const int base = (blockIdx.x * 4 + wv) * (32 * ITERS);  // 256 pts/wave
  const int off = (kg < 2) ? 0 : (3 + (kg - 2) * 8);

  // ---- prologue: load iter-0's 2x8 floats ----
  float v[2][8];
#pragma unroll
  for (int tt = 0; tt < 2; ++tt) {
    int p = base + tt * 16 + row;
    if (p > N - 1) p = N - 1;
    const float* xr = x + (long long)p * 19;
#pragma unroll
    for (int j = 0; j < 8; ++j) v[tt][j] = xr[off + j];
  }

#pragma unroll 2
  for (int it = 0; it < ITERS; ++it) {
    const int p0 = base + it * 32;

    // ---- prefetch iter+1's loads (in flight across the lgkm fences) ----
    float vn[2][8];
    {
      int pn0 = base + (it + 1 < ITERS ? it + 1 : it) * 32;
#pragma unroll
      for (int tt = 0; tt < 2; ++tt) {
        int p = pn0 + tt * 16 + row;
        if (p > N - 1) p = N - 1;
        const float* xr = x + (long long)p * 19;
#pragma unroll
        for (int j = 0; j < 8; ++j) vn[tt][j] = xr[off + j];
      }
    }

    // ---- encode both tiles from v (prefetched last iter) ----
    short8 a0[2];
#pragma unroll
    for (int tt = 0; tt < 2; ++tt) {
      float e[8];
      if (kg == 0) {
        float X = v[tt][0] * 2.f - 1.f, Y = v[tt][1] * 2.f - 1.f, Z = v[tt][2] * 2.f - 1.f;
        e[0] = 0.28209479177387814f;
        e[1] = -0.48860251190291987f * Y;
        e[2] = 0.48860251190291987f * Z;
        e[3] = -0.48860251190291987f * X;
        e[4] = 1.0925484305920792f * X * Y;
        e[5] = -1.0925484305920792f * Y * Z;
        e[6] = 0.94617469575756f * Z * Z - 0.31539156525252f;
        e[7] = -1.0925484305920792f * X * Z;
      } else if (kg == 1) {
        float X = v[tt][0] * 2.f - 1.f, Y = v[tt][1] * 2.f - 1.f, Z = v[tt][2] * 2.f - 1.f;
        float X2 = X * X, Y2 = Y * Y, Z2 = Z * Z;
        e[0] = 0.5462742152960396f * (X2 - Y2);
        e[1] = 0.5900435899266435f * Y * (-3.f * X2 + Y2);
        e[2] = 2.890611442640554f * X * Y * Z;
        e[3] = 0.4570457994644657f * Y * (1.f - 5.f * Z2);
        e[4] = 0.3731763325901154f * Z * (5.f * Z2 - 3.f);
        e[5] = 0.4570457994644657f * X * (1.f - 5.f * Z2);
        e[6] = 1.445305721320277f * Z * (X2 - Y2);
        e[7] = 0.5900435899266435f * X * (X2 - 3.f * Y2);
      } else {
#pragma unroll
        for (int j = 0; j < 8; ++j) e[j] = v[tt][j];
      }
#pragma unroll
      for (int j = 0; j < 8; ++j) a0[tt][j] = f2bf(e[j]);
    }

    // ---- layer 1: enc(16x32) @ W1(32x64), both tiles ----
    f32x4 c1[2][4];
#pragma unroll
    for (int tt = 0; tt < 2; ++tt)
#pragma unroll
      for (int cb = 0; cb < 4; ++cb) c1[tt][cb] = MFMA16(a0[tt], w1b[cb], zero);

    // relu -> h1 LDS (C layout: row = 4*kg + r, col = cb*16 + (lane&15))
#pragma unroll
    for (int tt = 0; tt < 2; ++tt)
#pragma unroll
      for (int cb = 0; cb < 4; ++cb)
#pragma unroll
        for (int r = 0; r < 4; ++r)
          h1s[wv][tt][kg * 4 + r][cb * 16 + row] = f2bf(fmaxf(c1[tt][cb][r], 0.f));
    WAVE_LDS_FENCE();  // wave-private transpose: lgkm drain only, no barrier

    // A-fragments of h1: lane reads h1[row][32*s + 8*kg .. +8]
    short8 a1[2][2];
#pragma unroll
    for (int tt = 0; tt < 2; ++tt)
#pragma unroll
      for (int s = 0; s < 2; ++s) {
        short4v lo = *(const short4v*)&h1s[wv][tt][row][s * 32 + kg * 8];
        short4v hi = *(const short4v*)&h1s[wv][tt][row][s * 32 + kg * 8 + 4];
        a1[tt][s] = __builtin_shufflevector(lo, hi, 0, 1, 2, 3, 4, 5, 6, 7);
      }

    // ---- layer 2: h1(16x64) @ W2(64x64), both tiles ----
    f32x4 c2[2][4];
#pragma unroll
    for (int tt = 0; tt < 2; ++tt)
#pragma unroll
      for (int cb = 0; cb < 4; ++cb) {
        f32x4 acc = MFMA16(a1[tt][0], w2b[0][cb], zero);
        c2[tt][cb] = MFMA16(a1[tt][1], w2b[1][cb], acc);
      }

    // relu -> h2 LDS
#pragma unroll
    for (int tt = 0; tt < 2; ++tt)
#pragma unroll
      for (int cb = 0; cb < 4; ++cb)
#pragma unroll
        for (int r = 0; r < 4; ++r)
          h2s[wv][tt][kg * 4 + r][cb * 16 + row] = f2bf(fmaxf(c2[tt][cb][r], 0.f));
    WAVE_LDS_FENCE();

    short8 a2[2][2];
#pragma unroll
    for (int tt = 0; tt < 2; ++tt)
#pragma unroll
      for (int s = 0; s < 2; ++s) {
        short4v lo = *(const short4v*)&h2s[wv][tt][row][s * 32 + kg * 8];
        short4v hi = *(const short4v*)&h2s[wv][tt][row][s * 32 + kg * 8 + 4];
        a2[tt][s] = __builtin_shufflevector(lo, hi, 0, 1, 2, 3, 4, 5, 6, 7);
      }

    // ---- layer 3 + store, both tiles ----
#pragma unroll
    for (int tt = 0; tt < 2; ++tt) {
      f32x4 c3 = MFMA16(a2[tt][0], w3b[0], zero);
      c3 = MFMA16(a2[tt][1], w3b[1], c3);
      if (row < 3) {
#pragma unroll
        for (int r = 0; r < 4; ++r) {
          const int q = p0 + tt * 16 + kg * 4 + r;
          if (q < N) out[(long long)q * 3 + row] = c3[r];
        }
      }
    }

    // rotate prefetch buffer (unroll-2 makes this a pure rename)
#pragma unroll
    for (int tt = 0; tt < 2; ++tt)
#pragma unroll
      for (int j = 0; j < 8; ++j) v[tt][j] = vn[tt][j];
  }
}

extern "C" void kernel_launch(void* const* d_in, const int* in_sizes, int n_in,
                              void* d_out, int out_size, void* d_ws, size_t ws_size,
                              hipStream_t stream) {
  (void)d_ws; (void)ws_size; (void)n_in; (void)out_size;
  const float* x = (const float*)d_in[0];
  const float* W1 = (const float*)d_in[1];
  const float* W2 = (const float*)d_in[2];
  const float* W3 = (const float*)d_in[3];
  float* out = (float*)d_out;
  const int N = in_sizes[0] / 19;            // 2,097,152
  const int ppb = 4 * 32 * ITERS;            // 1024 points per block
  const int blocks = (N + ppb - 1) / ppb;    // 2048
  fused_color_mlp<<<blocks, 256, 0, stream>>>(x, W1, W2, W3, out, N);
}